// Round 13
// baseline (665.001 us; speedup 1.0000x reference)
//
#include <hip/hip_runtime.h>
#include <stdint.h>

typedef unsigned short u16;
typedef short bf16x8 __attribute__((ext_vector_type(8)));
typedef float f32x4 __attribute__((ext_vector_type(4)));
typedef u16 u16x8 __attribute__((ext_vector_type(8)));
typedef u16 u16x4v __attribute__((ext_vector_type(4)));
typedef uint32_t u32x4 __attribute__((ext_vector_type(4)));

#define EMBED 512
#define NBATCH 8
#define QLEN 2048
#define KLEN 4096

__device__ __forceinline__ u16 f2bf(float f) {
  uint32_t u = __builtin_bit_cast(uint32_t, f);
  u += 0x7fffu + ((u >> 16) & 1u);   // RNE
  return (u16)(u >> 16);
}
__device__ __forceinline__ float bf2f(u16 b) {
  return __builtin_bit_cast(float, (uint32_t)b << 16);
}

// async global->LDS, 16B per lane. LDS dest = wave-uniform base + lane*16 (linear).
__device__ __forceinline__ void gload_lds16(const void* g, void* lds) {
  __builtin_amdgcn_global_load_lds(
      (__attribute__((address_space(1))) void*)(uintptr_t)g,
      (__attribute__((address_space(3))) void*)(uint32_t)(uintptr_t)lds,
      16, 0, 0);
}

// one kernel converts all six fp32 inputs into the contiguous bf16 region at
// the start of ws (layout: xb | yb | Wqb | Wkb | Wvb | Wob)
__global__ __launch_bounds__(256) void cvt_all_kernel(
    const float* __restrict__ x, const float* __restrict__ y,
    const float* __restrict__ wq, const float* __restrict__ wk,
    const float* __restrict__ wv, const float* __restrict__ wo,
    u16* __restrict__ dst) {
  const int64_t B0 = 2097152;        // nx/4
  const int64_t B1 = B0 + 4194304;   // + ny/4
  const int64_t B2 = B1 + 65536;
  const int64_t B3 = B2 + 65536;
  const int64_t B4 = B3 + 65536;
  int64_t i = (int64_t)blockIdx.x * 256 + threadIdx.x;  // float4 units
  const float* src; int64_t off;
  if (i < B0)      { src = x;  off = 0;  }
  else if (i < B1) { src = y;  off = B0; }
  else if (i < B2) { src = wq; off = B1; }
  else if (i < B3) { src = wk; off = B2; }
  else if (i < B4) { src = wv; off = B3; }
  else             { src = wo; off = B4; }
  float4 f = ((const float4*)src)[i - off];
  u16x4v o = { f2bf(f.x), f2bf(f.y), f2bf(f.z), f2bf(f.w) };
  ((u16x4v*)dst)[i] = o;
}

// ---------------------------------------------------------------------------
// Generic C = A * B^T   (A: MxK bf16 row-major, B: NxK bf16 row-major)
// 128x128 tile, BK=64, 4 waves (each 64x64), mfma_f32_16x16x32_bf16.
// ---------------------------------------------------------------------------
constexpr int EPI_BF16 = 0;        // C bf16 [M][N]
constexpr int EPI_BF16_SCALE = 1;  // C bf16 = acc*scale
constexpr int EPI_BF16_TRANS = 2;  // V in FRAGMENT-MAJOR layout (see below)
constexpr int EPI_F32_RESID = 3;   // C f32 = acc + xres + bias[col]

template <int MODE>
__global__ __launch_bounds__(256, 2) void gemm_bt(
    const u16* __restrict__ A, const u16* __restrict__ B, void* __restrict__ Cv,
    int M, int N, int K,
    int64_t aBatch, int64_t bBatch, int64_t cBatch,
    float scale, const float* __restrict__ xres, const float* __restrict__ bias,
    u16* __restrict__ Vt) {
  __shared__ __align__(16) u16 As[128 * 64];
  __shared__ __align__(16) u16 Bs[128 * 64];

  const int tid = threadIdx.x;
  const int wave = tid >> 6;
  const int lane = tid & 63;
  const int bz = blockIdx.z;
  const int row0 = blockIdx.x * 128;
  const int col0 = blockIdx.y * 128;
  const u16* Ab = A + (int64_t)bz * aBatch;
  const u16* Bb = B + (int64_t)bz * bBatch;

  const int srow = wave * 32 + (lane >> 3);
  const int scol = (lane & 7) * 8;
  const u16* aSrc = Ab + (int64_t)(row0 + srow) * K + scol;
  const u16* bSrc = Bb + (int64_t)(col0 + srow) * K + scol;

  const int wm = (wave >> 1) * 64;
  const int wn = (wave & 1) * 64;
  const int fr = lane & 15;
  const int fq = lane >> 4;

  f32x4 acc[4][4];
#pragma unroll
  for (int mi = 0; mi < 4; ++mi)
#pragma unroll
    for (int ni = 0; ni < 4; ++ni) acc[mi][ni] = 0.0f;

  const int nkt = K >> 6;
  for (int kt = 0; kt < nkt; ++kt) {
    __syncthreads();
    const u16* aS = aSrc + kt * 64;
    const u16* bS = bSrc + kt * 64;
#pragma unroll
    for (int i = 0; i < 4; ++i) {
      gload_lds16(aS + (int64_t)(i * 8) * K, &As[(wave * 32 + i * 8) * 64]);
      gload_lds16(bS + (int64_t)(i * 8) * K, &Bs[(wave * 32 + i * 8) * 64]);
    }
    __syncthreads();
#pragma unroll
    for (int ks = 0; ks < 2; ++ks) {
      bf16x8 af[4], bfr[4];
#pragma unroll
      for (int mi = 0; mi < 4; ++mi)
        af[mi] = *(const bf16x8*)&As[(wm + mi * 16 + fr) * 64 + ks * 32 + fq * 8];
#pragma unroll
      for (int ni = 0; ni < 4; ++ni)
        bfr[ni] = *(const bf16x8*)&Bs[(wn + ni * 16 + fr) * 64 + ks * 32 + fq * 8];
#pragma unroll
      for (int mi = 0; mi < 4; ++mi)
#pragma unroll
        for (int ni = 0; ni < 4; ++ni)
          acc[mi][ni] = __builtin_amdgcn_mfma_f32_16x16x32_bf16(af[mi], bfr[ni],
                                                                acc[mi][ni], 0, 0, 0);
    }
  }

  // C/D layout: col = lane&15, row = (lane>>4)*4 + reg  [m89-verified]
  if constexpr (MODE == EPI_BF16 || MODE == EPI_BF16_SCALE) {
    u16* C = (u16*)Cv + (int64_t)bz * cBatch;
#pragma unroll
    for (int mi = 0; mi < 4; ++mi) {
      const int rowb = row0 + wm + mi * 16 + fq * 4;
#pragma unroll
      for (int ni = 0; ni < 4; ++ni) {
        const int col = col0 + wn + ni * 16 + fr;
#pragma unroll
        for (int r = 0; r < 4; ++r) {
          float v = acc[mi][ni][r];
          if constexpr (MODE == EPI_BF16_SCALE) v *= scale;
          C[(int64_t)(rowb + r) * N + col] = f2bf(v);
        }
      }
    }
  } else if constexpr (MODE == EPI_BF16_TRANS) {
    // FRAGMENT-MAJOR V: Vf[((nb*128 + t)*32 + dt)*512 + (kq*16 + dr)*8 + ke]
    //   t = key tile (k>>5), kq = (k>>3)&3, ke = k&7, dt = d>>4, dr = d&15.
    // This is the exact per-lane PV B-fragment order: attn lane L reads 16B
    // at frag_base + L*16 -> one coalesced 1KB dwordx4 per fragment (fixes
    // R7's 16-way transaction split; lets attn drop V from LDS entirely).
#pragma unroll
    for (int mi = 0; mi < 4; ++mi) {
      const int rowb = row0 + wm + mi * 16 + fq * 4;
      const int nb = rowb >> 12;
      const int kk = rowb & 4095;       // k within batch; 4-aligned
      const int tt = kk >> 5;
      const int kq = (kk >> 3) & 3;
      const int ke = kk & 7;            // 0 or 4
#pragma unroll
      for (int ni = 0; ni < 4; ++ni) {
        const int col = col0 + wn + ni * 16 + fr;
        const int dt = col >> 4;
        const int dr = col & 15;
        u16x4v o = { f2bf(acc[mi][ni][0]), f2bf(acc[mi][ni][1]),
                     f2bf(acc[mi][ni][2]), f2bf(acc[mi][ni][3]) };
        *(u16x4v*)&Vt[(((int64_t)nb * 128 + tt) * 32 + dt) * 512 +
                      (kq * 16 + dr) * 8 + ke] = o;
      }
    }
  } else {  // EPI_F32_RESID
    float* C = (float*)Cv;
#pragma unroll
    for (int mi = 0; mi < 4; ++mi) {
      const int rowb = row0 + wm + mi * 16 + fq * 4;
#pragma unroll
      for (int ni = 0; ni < 4; ++ni) {
        const int col = col0 + wn + ni * 16 + fr;
        const float bv = bias[col];
#pragma unroll
        for (int r = 0; r < 4; ++r) {
          const int64_t idx = (int64_t)(rowb + r) * N + col;
          C[idx] = acc[mi][ni][r] + xres[idx] + bv;
        }
      }
    }
  }
}

// ---------------------------------------------------------------------------
// Fused flash attention — R8 structure, V from GLOBAL in fragment-major form.
//
// R12 post-mortem: setprio perturbed regalloc (VGPR 220->256, spills) and
// cost ~9us -> reverted. R8 (322.6us) kept.
//
// R13: R8's LDS pipe was ~65% busy (3900cy/tile: K reads 1536 + V reads 1536
// + staging 256 + conflicts 576) and poorly overlapped with MFMA (1242) and
// VALU (~1200). V now comes straight from global in the fragment-major
// layout the V-GEMM writes (one coalesced 1KB dwordx4 per PV B-fragment —
// fixes R7's 16-way split). V's 128KB/tile/CU moves to the VMEM/L2 pipe
// (~2340cy at 56B/cy/CU, L2-hot via batch->XCD swizzle) which runs in
// PARALLEL with LDS (now K-only, ~2200cy) and MFMA. Loads issue at tile-top
// (16) and post-softmax (16) with ~2000cy slack each. LDS 131->64KB; V
// staging writes + V bank conflicts gone; register peak same as R8 (~220).
// ---------------------------------------------------------------------------
__global__ __launch_bounds__(256, 1) void attn_kernel(
    const u16* __restrict__ Qm, const u16* __restrict__ Km,
    const u16* __restrict__ Vf, u16* __restrict__ O) {
  __shared__ __align__(16) u16 Ks[2][32 * 512];   // 2 x 32KB (K only)

  const int tid = threadIdx.x;
  const int w = tid >> 6;
  const int lane = tid & 63;
  const int fr = lane & 15, fq = lane >> 4;
  const int s7 = fr & 7;
  const int nb = blockIdx.x & 7;   // batch -> XCD (round-robin dispatch)
  const int qt = blockIdx.x >> 3;

  // Q B-frags: lane fr = q-row (w*16+fr), fq*8 = d-chunk
  bf16x8 q[16];
  {
    const u16* Qb = Qm + ((int64_t)nb * QLEN + qt * 64 + w * 16 + fr) * EMBED + fq * 8;
#pragma unroll
    for (int kc = 0; kc < 16; ++kc) q[kc] = *(const bf16x8*)&Qb[kc * 32];
  }

  f32x4 o[32];  // o[dt][r]: q row w*16 + fq*4+r, d col dt*16+fr
#pragma unroll
  for (int i = 0; i < 32; ++i) o[i] = 0.0f;
  float mrun = -1e30f, lrun = 0.0f;  // per-lane scalars (q = fr)

  const u16* Kb = Km + (int64_t)nb * KLEN * EMBED;
  // fragment-major V, per-batch base; lane L's 16B at frag*512 + L*8 (u16)
  const u16* Vb = Vf + (int64_t)nb * 128 * 32 * 512 + lane * 8;

  // prologue: stage K tile 0 into slot 0 (swizzle: src chunk = lane ^ (row&7))
  {
    const u16* srcK = Kb + (int64_t)(w * 8) * EMBED;
#pragma unroll
    for (int i = 0; i < 8; ++i)
      gload_lds16(srcK + (int64_t)i * EMBED + (lane ^ i) * 8, &Ks[0][(w * 8 + i) * 512]);
  }
  __syncthreads();

  const int NT = KLEN / 32;  // 128
  for (int t = 0; t < NT; ++t) {
    const int cur = t & 1;
    // prefetch K[t+1] into other slot (drained by iter-end sync)
    if (t + 1 < NT) {
      const u16* srcK = Kb + ((int64_t)(t + 1) * 32 + w * 8) * EMBED;
#pragma unroll
      for (int i = 0; i < 8; ++i)
        gload_lds16(srcK + (int64_t)i * EMBED + (lane ^ i) * 8,
                    &Ks[cur ^ 1][(w * 8 + i) * 512]);
    }

    // first 16 V fragments (d cols 0..255): coalesced global loads, L2-hot;
    // latency hides under the QK MFMA cluster + softmax
    bf16x8 vA[16];
#pragma unroll
    for (int dt = 0; dt < 16; ++dt)
      vA[dt] = *(const bf16x8*)&Vb[((int64_t)t * 32 + dt) * 512];

    // S^T = K Q^T: lane fr = q, keys ni*16 + fq*4 + r
    const u16* Kc = Ks[cur];
    f32x4 s0 = 0.0f, s1 = 0.0f;
#pragma unroll
    for (int kc = 0; kc < 16; ++kc) {
      bf16x8 k0 = *(const bf16x8*)&Kc[(fr)*512 + (((kc * 4 + fq) ^ s7) * 8)];
      bf16x8 k1 = *(const bf16x8*)&Kc[(16 + fr) * 512 + (((kc * 4 + fq) ^ s7) * 8)];
      s0 = __builtin_amdgcn_mfma_f32_16x16x32_bf16(k0, q[kc], s0, 0, 0, 0);
      s1 = __builtin_amdgcn_mfma_f32_16x16x32_bf16(k1, q[kc], s1, 0, 0, 0);
    }

    // in-register online softmax (defer-max, THR=8)
    float mt = fmaxf(fmaxf(fmaxf(s0[0], s0[1]), fmaxf(s0[2], s0[3])),
                     fmaxf(fmaxf(s1[0], s1[1]), fmaxf(s1[2], s1[3])));
    mt = fmaxf(mt, __shfl_xor(mt, 16));
    mt = fmaxf(mt, __shfl_xor(mt, 32));
    float alpha = 1.0f;
    if (!__all(mt <= mrun + 8.0f)) {
      const float mn = fmaxf(mrun, mt);
      alpha = __expf(mrun - mn);
      lrun *= alpha;
      mrun = mn;
    }
    float p0[4], p1[4];
    float rs = 0.0f;
#pragma unroll
    for (int r = 0; r < 4; ++r) {
      p0[r] = __expf(s0[r] - mrun);
      p1[r] = __expf(s1[r] - mrun);
      rs += p0[r] + p1[r];
    }
    rs += __shfl_xor(rs, 16);
    rs += __shfl_xor(rs, 32);
    lrun += rs;

    // second 16 V fragments (d cols 256..511): latency hides under vA MFMAs
    bf16x8 vB[16];
#pragma unroll
    for (int dt = 0; dt < 16; ++dt)
      vB[dt] = *(const bf16x8*)&Vb[((int64_t)t * 32 + 16 + dt) * 512];

    // pack p -> 4 dwords (lo = keys 0-15 slice, hi = keys 16-31 slice)
    const uint32_t lo0 = (uint32_t)f2bf(p0[0]) | ((uint32_t)f2bf(p0[1]) << 16);
    const uint32_t lo1 = (uint32_t)f2bf(p0[2]) | ((uint32_t)f2bf(p0[3]) << 16);
    const uint32_t hi0 = (uint32_t)f2bf(p1[0]) | ((uint32_t)f2bf(p1[1]) << 16);
    const uint32_t hi1 = (uint32_t)f2bf(p1[2]) | ((uint32_t)f2bf(p1[3]) << 16);
    // repack to PV A-frag: lane (fr,fq) needs k = fq*8..fq*8+7 for q=fr
    const int srcA = fr + (((fq << 1) & 3) << 4);
    const int srcB = srcA + 16;
    const bool useHi = (fq >= 2);
    const uint32_t aLo0 = __shfl(lo0, srcA), aHi0 = __shfl(hi0, srcA);
    const uint32_t aLo1 = __shfl(lo1, srcA), aHi1 = __shfl(hi1, srcA);
    const uint32_t bLo0 = __shfl(lo0, srcB), bHi0 = __shfl(hi0, srcB);
    const uint32_t bLo1 = __shfl(lo1, srcB), bHi1 = __shfl(hi1, srcB);
    u32x4 pd;
    pd[0] = useHi ? aHi0 : aLo0;
    pd[1] = useHi ? aHi1 : aLo1;
    pd[2] = useHi ? bHi0 : bLo0;
    pd[3] = useHi ? bHi1 : bLo1;
    const bf16x8 pb = __builtin_bit_cast(bf16x8, pd);

    // rescale o (o rows are q = fq*4+r -> fetch those rows' alphas)
    if (__any(alpha != 1.0f)) {
      float ra[4];
#pragma unroll
      for (int r = 0; r < 4; ++r) ra[r] = __shfl(alpha, (fq << 2) + r);
#pragma unroll
      for (int dt = 0; dt < 32; ++dt)
#pragma unroll
        for (int r = 0; r < 4; ++r) o[dt][r] *= ra[r];
    }

    // PV: o[dt] += pb (A: q-rows) x V B-frag (from global regs)
#pragma unroll
    for (int dt = 0; dt < 16; ++dt)
      o[dt] = __builtin_amdgcn_mfma_f32_16x16x32_bf16(pb, vA[dt], o[dt], 0, 0, 0);
#pragma unroll
    for (int dt = 0; dt < 16; ++dt)
      o[16 + dt] = __builtin_amdgcn_mfma_f32_16x16x32_bf16(pb, vB[dt], o[16 + dt],
                                                           0, 0, 0);

    __syncthreads();  // staging drain; all waves done reading cur K slot
  }

  // normalize + store (l for q-row fq*4+r lives in lane fq*4+r)
  float linv[4];
#pragma unroll
  for (int r = 0; r < 4; ++r) linv[r] = 1.0f / __shfl(lrun, (fq << 2) + r);
  u16* Ob = O + ((int64_t)nb * QLEN + qt * 64 + w * 16) * EMBED;
#pragma unroll
  for (int dt = 0; dt < 32; ++dt)
#pragma unroll
    for (int r = 0; r < 4; ++r)
      Ob[(int64_t)((fq << 2) + r) * EMBED + dt * 16 + fr] = f2bf(o[dt][r] * linv[r]);
}

extern "C" void kernel_launch(void* const* d_in, const int* in_sizes, int n_in,
                              void* d_out, int out_size, void* d_ws, size_t ws_size,
                              hipStream_t stream) {
  const float* x  = (const float*)d_in[0];
  const float* y  = (const float*)d_in[1];
  const float* Wq = (const float*)d_in[2];
  const float* Wk = (const float*)d_in[3];
  const float* Wv = (const float*)d_in[4];
  const float* Wo = (const float*)d_in[5];
  const float* bo = (const float*)d_in[6];
  float* out = (float*)d_out;

  const int64_t nx = (int64_t)NBATCH * QLEN * EMBED;  // 8,388,608
  const int64_t ny = (int64_t)NBATCH * KLEN * EMBED;  // 16,777,216
  const int64_t nw = (int64_t)EMBED * EMBED;          // 262,144

  // ws layout (bf16): xb | yb | Wqb | Wkb | Wvb | Wob | Qm | Km | Vt  (~136MB)
  u16* w   = (u16*)d_ws;
  u16* xb  = w;            // dead after Q projection
  u16* O   = w; w += nx;   // attn output overlays xb
  u16* yb  = w; w += ny;
  u16* Wqb = w; w += nw;
  u16* Wkb = w; w += nw;
  u16* Wvb = w; w += nw;
  u16* Wob = w; w += nw;
  u16* Qm  = w; w += nx;
  u16* Km  = w; w += ny;
  u16* Vt  = w; w += ny;   // fragment-major V: [8][128][32][64 lanes][8]

  // one fused fp32->bf16 conversion over the contiguous region
  cvt_all_kernel<<<25600, 256, 0, stream>>>(x, y, Wq, Wk, Wv, Wo, xb);

  // Qm = (x@Wq^T) * 1/sqrt(512)
  const float scal = 0.04419417382415922f;
  gemm_bt<EPI_BF16_SCALE><<<dim3(128, 4, 1), 256, 0, stream>>>(
      xb, Wqb, Qm, 16384, EMBED, EMBED, 0, 0, 0, scal, nullptr, nullptr, nullptr);
  gemm_bt<EPI_BF16><<<dim3(256, 4, 1), 256, 0, stream>>>(
      yb, Wkb, Km, 32768, EMBED, EMBED, 0, 0, 0, 1.f, nullptr, nullptr, nullptr);
  gemm_bt<EPI_BF16_TRANS><<<dim3(256, 4, 1), 256, 0, stream>>>(
      yb, Wvb, nullptr, 32768, EMBED, EMBED, 0, 0, 0, 1.f, nullptr, nullptr, Vt);

  // fused attention (writes O over the dead xb slot)
  attn_kernel<<<NBATCH * 32, 256, 0, stream>>>(Qm, Km, Vt, O);

  // out = x + O @ Wo^T + bo   (fp32 epilogue)
  gemm_bt<EPI_F32_RESID><<<dim3(128, 4, 1), 256, 0, stream>>>(
      O, Wob, out, 16384, EMBED, EMBED, 0, 0, 0, 1.f, x, bo, nullptr);
}

// Round 15
// 392.651 us; speedup vs baseline: 1.6936x; 1.6936x over previous
//
#include <hip/hip_runtime.h>
#include <stdint.h>

typedef unsigned short u16;
typedef short bf16x8 __attribute__((ext_vector_type(8)));
typedef float f32x4 __attribute__((ext_vector_type(4)));
typedef u16 u16x8 __attribute__((ext_vector_type(8)));
typedef u16 u16x4v __attribute__((ext_vector_type(4)));
typedef uint32_t u32x4 __attribute__((ext_vector_type(4)));

#define EMBED 512
#define NBATCH 8
#define QLEN 2048
#define KLEN 4096

__device__ __forceinline__ u16 f2bf(float f) {
  uint32_t u = __builtin_bit_cast(uint32_t, f);
  u += 0x7fffu + ((u >> 16) & 1u);   // RNE
  return (u16)(u >> 16);
}
__device__ __forceinline__ float bf2f(u16 b) {
  return __builtin_bit_cast(float, (uint32_t)b << 16);
}

// async global->LDS, 16B per lane. LDS dest = wave-uniform base + lane*16 (linear).
__device__ __forceinline__ void gload_lds16(const void* g, void* lds) {
  __builtin_amdgcn_global_load_lds(
      (__attribute__((address_space(1))) void*)(uintptr_t)g,
      (__attribute__((address_space(3))) void*)(uint32_t)(uintptr_t)lds,
      16, 0, 0);
}

// one kernel converts all six fp32 inputs into the contiguous bf16 region at
// the start of ws (layout: xb | yb | Wqb | Wkb | Wvb | Wob)
__global__ __launch_bounds__(256) void cvt_all_kernel(
    const float* __restrict__ x, const float* __restrict__ y,
    const float* __restrict__ wq, const float* __restrict__ wk,
    const float* __restrict__ wv, const float* __restrict__ wo,
    u16* __restrict__ dst) {
  const int64_t B0 = 2097152;        // nx/4
  const int64_t B1 = B0 + 4194304;   // + ny/4
  const int64_t B2 = B1 + 65536;
  const int64_t B3 = B2 + 65536;
  const int64_t B4 = B3 + 65536;
  int64_t i = (int64_t)blockIdx.x * 256 + threadIdx.x;  // float4 units
  const float* src; int64_t off;
  if (i < B0)      { src = x;  off = 0;  }
  else if (i < B1) { src = y;  off = B0; }
  else if (i < B2) { src = wq; off = B1; }
  else if (i < B3) { src = wk; off = B2; }
  else if (i < B4) { src = wv; off = B3; }
  else             { src = wo; off = B4; }
  float4 f = ((const float4*)src)[i - off];
  u16x4v o = { f2bf(f.x), f2bf(f.y), f2bf(f.z), f2bf(f.w) };
  ((u16x4v*)dst)[i] = o;
}

// ---------------------------------------------------------------------------
// Generic C = A * B^T   (A: MxK bf16 row-major, B: NxK bf16 row-major)
// 128x128 tile, BK=64, 4 waves (each 64x64), mfma_f32_16x16x32_bf16.
// ---------------------------------------------------------------------------
constexpr int EPI_BF16 = 0;        // C bf16 [M][N]
constexpr int EPI_BF16_SCALE = 1;  // C bf16 = acc*scale
constexpr int EPI_F32_RESID = 3;   // C f32 = acc + xres + bias[col]

template <int MODE>
__global__ __launch_bounds__(256, 2) void gemm_bt(
    const u16* __restrict__ A, const u16* __restrict__ B, void* __restrict__ Cv,
    int M, int N, int K,
    float scale, const float* __restrict__ xres, const float* __restrict__ bias) {
  __shared__ __align__(16) u16 As[128 * 64];
  __shared__ __align__(16) u16 Bs[128 * 64];

  const int tid = threadIdx.x;
  const int wave = tid >> 6;
  const int lane = tid & 63;
  const int row0 = blockIdx.x * 128;
  const int col0 = blockIdx.y * 128;

  const int srow = wave * 32 + (lane >> 3);
  const int scol = (lane & 7) * 8;
  const u16* aSrc = A + (int64_t)(row0 + srow) * K + scol;
  const u16* bSrc = B + (int64_t)(col0 + srow) * K + scol;

  const int wm = (wave >> 1) * 64;
  const int wn = (wave & 1) * 64;
  const int fr = lane & 15;
  const int fq = lane >> 4;

  f32x4 acc[4][4];
#pragma unroll
  for (int mi = 0; mi < 4; ++mi)
#pragma unroll
    for (int ni = 0; ni < 4; ++ni) acc[mi][ni] = 0.0f;

  const int nkt = K >> 6;
  for (int kt = 0; kt < nkt; ++kt) {
    __syncthreads();
    const u16* aS = aSrc + kt * 64;
    const u16* bS = bSrc + kt * 64;
#pragma unroll
    for (int i = 0; i < 4; ++i) {
      gload_lds16(aS + (int64_t)(i * 8) * K, &As[(wave * 32 + i * 8) * 64]);
      gload_lds16(bS + (int64_t)(i * 8) * K, &Bs[(wave * 32 + i * 8) * 64]);
    }
    __syncthreads();
#pragma unroll
    for (int ks = 0; ks < 2; ++ks) {
      bf16x8 af[4], bfr[4];
#pragma unroll
      for (int mi = 0; mi < 4; ++mi)
        af[mi] = *(const bf16x8*)&As[(wm + mi * 16 + fr) * 64 + ks * 32 + fq * 8];
#pragma unroll
      for (int ni = 0; ni < 4; ++ni)
        bfr[ni] = *(const bf16x8*)&Bs[(wn + ni * 16 + fr) * 64 + ks * 32 + fq * 8];
#pragma unroll
      for (int mi = 0; mi < 4; ++mi)
#pragma unroll
        for (int ni = 0; ni < 4; ++ni)
          acc[mi][ni] = __builtin_amdgcn_mfma_f32_16x16x32_bf16(af[mi], bfr[ni],
                                                                acc[mi][ni], 0, 0, 0);
    }
  }

  // C/D layout: col = lane&15, row = (lane>>4)*4 + reg  [m89-verified]
  if constexpr (MODE == EPI_BF16 || MODE == EPI_BF16_SCALE) {
    u16* C = (u16*)Cv;
#pragma unroll
    for (int mi = 0; mi < 4; ++mi) {
      const int rowb = row0 + wm + mi * 16 + fq * 4;
#pragma unroll
      for (int ni = 0; ni < 4; ++ni) {
        const int col = col0 + wn + ni * 16 + fr;
#pragma unroll
        for (int r = 0; r < 4; ++r) {
          float v = acc[mi][ni][r];
          if constexpr (MODE == EPI_BF16_SCALE) v *= scale;
          C[(int64_t)(rowb + r) * N + col] = f2bf(v);
        }
      }
    }
  } else {  // EPI_F32_RESID
    float* C = (float*)Cv;
#pragma unroll
    for (int mi = 0; mi < 4; ++mi) {
      const int rowb = row0 + wm + mi * 16 + fq * 4;
#pragma unroll
      for (int ni = 0; ni < 4; ++ni) {
        const int col = col0 + wn + ni * 16 + fr;
        const float bv = bias[col];
#pragma unroll
        for (int r = 0; r < 4; ++r) {
          const int64_t idx = (int64_t)(rowb + r) * N + col;
          C[idx] = acc[mi][ni][r] + xres[idx] + bv;
        }
      }
    }
  }
}

// ---------------------------------------------------------------------------
// Fused K+V projection: Km = y@Wk^T (row-major), Vt = y@Wv^T (d-major).
// Shares the A (yb) staging between both products: A-tile loaded ONCE per
// K-step, two B-tiles (Wk, Wv), two accumulator sets, two epilogues. Halves
// the combined A traffic of the former two gemm_bt launches and saves one
// dispatch. LDS 48KB -> 2 blocks/CU; acc 2x64 AGPR + ~90 arch VGPR <= 256.
// ---------------------------------------------------------------------------
__global__ __launch_bounds__(256, 2) void gemm_kv(
    const u16* __restrict__ A, const u16* __restrict__ Bk,
    const u16* __restrict__ Bv, u16* __restrict__ Km, u16* __restrict__ Vt) {
  __shared__ __align__(16) u16 As[128 * 64];
  __shared__ __align__(16) u16 Bks[128 * 64];
  __shared__ __align__(16) u16 Bvs[128 * 64];

  const int tid = threadIdx.x;
  const int wave = tid >> 6;
  const int lane = tid & 63;
  const int K = EMBED;              // inner dim
  const int row0 = blockIdx.x * 128;
  const int col0 = blockIdx.y * 128;

  const int srow = wave * 32 + (lane >> 3);
  const int scol = (lane & 7) * 8;
  const u16* aSrc = A + (int64_t)(row0 + srow) * K + scol;
  const u16* bkSrc = Bk + (int64_t)(col0 + srow) * K + scol;
  const u16* bvSrc = Bv + (int64_t)(col0 + srow) * K + scol;

  const int wm = (wave >> 1) * 64;
  const int wn = (wave & 1) * 64;
  const int fr = lane & 15;
  const int fq = lane >> 4;

  f32x4 accK[4][4], accV[4][4];
#pragma unroll
  for (int mi = 0; mi < 4; ++mi)
#pragma unroll
    for (int ni = 0; ni < 4; ++ni) { accK[mi][ni] = 0.0f; accV[mi][ni] = 0.0f; }

  const int nkt = K >> 6;  // 8
  for (int kt = 0; kt < nkt; ++kt) {
    __syncthreads();
#pragma unroll
    for (int i = 0; i < 4; ++i) {
      gload_lds16(aSrc + kt * 64 + (int64_t)(i * 8) * K, &As[(wave * 32 + i * 8) * 64]);
      gload_lds16(bkSrc + kt * 64 + (int64_t)(i * 8) * K, &Bks[(wave * 32 + i * 8) * 64]);
      gload_lds16(bvSrc + kt * 64 + (int64_t)(i * 8) * K, &Bvs[(wave * 32 + i * 8) * 64]);
    }
    __syncthreads();
#pragma unroll
    for (int ks = 0; ks < 2; ++ks) {
      bf16x8 af[4], bfk[4], bfv[4];
#pragma unroll
      for (int mi = 0; mi < 4; ++mi)
        af[mi] = *(const bf16x8*)&As[(wm + mi * 16 + fr) * 64 + ks * 32 + fq * 8];
#pragma unroll
      for (int ni = 0; ni < 4; ++ni) {
        bfk[ni] = *(const bf16x8*)&Bks[(wn + ni * 16 + fr) * 64 + ks * 32 + fq * 8];
        bfv[ni] = *(const bf16x8*)&Bvs[(wn + ni * 16 + fr) * 64 + ks * 32 + fq * 8];
      }
#pragma unroll
      for (int mi = 0; mi < 4; ++mi)
#pragma unroll
        for (int ni = 0; ni < 4; ++ni) {
          accK[mi][ni] = __builtin_amdgcn_mfma_f32_16x16x32_bf16(af[mi], bfk[ni],
                                                                 accK[mi][ni], 0, 0, 0);
          accV[mi][ni] = __builtin_amdgcn_mfma_f32_16x16x32_bf16(af[mi], bfv[ni],
                                                                 accV[mi][ni], 0, 0, 0);
        }
    }
  }

  // K epilogue: row-major Km[row][col], N = EMBED
#pragma unroll
  for (int mi = 0; mi < 4; ++mi) {
    const int rowb = row0 + wm + mi * 16 + fq * 4;
#pragma unroll
    for (int ni = 0; ni < 4; ++ni) {
      const int col = col0 + wn + ni * 16 + fr;
#pragma unroll
      for (int r = 0; r < 4; ++r)
        Km[(int64_t)(rowb + r) * EMBED + col] = f2bf(accK[mi][ni][r]);
    }
  }
  // V epilogue: d-major Vt[nb][d=col][k=row%4096]  (R8 attn layout)
#pragma unroll
  for (int mi = 0; mi < 4; ++mi) {
    const int rowb = row0 + wm + mi * 16 + fq * 4;
    const int nb = rowb >> 12;
    const int kk = rowb & 4095;
#pragma unroll
    for (int ni = 0; ni < 4; ++ni) {
      const int col = col0 + wn + ni * 16 + fr;
      u16x4v o = { f2bf(accV[mi][ni][0]), f2bf(accV[mi][ni][1]),
                   f2bf(accV[mi][ni][2]), f2bf(accV[mi][ni][3]) };
      *(u16x4v*)&Vt[((int64_t)nb * EMBED + col) * KLEN + kk] = o;
    }
  }
}

// ---------------------------------------------------------------------------
// Fused flash attention — EXACT R8 (session best: attn 322.6us, verified).
//
// R14 post-mortem: V-from-global failed correctness with issue-order-only
// changes (compiler scheduling hazard around global_load_lds + 32 plain
// global loads, invisible at HIP level). Line closed after three failures
// (R7 txn-split, R13 vmcnt stall, R14 wrong data). R8 restored verbatim.
//
// R8: swapped QK (lane fr = own q-row; per-lane scalar softmax, 2 shfl_xor),
// P repacked in-register to PV A-frag (8 shfl + selects), K+V tiles in LDS
// (dbuf, one barrier/tile, waves skew freely). V swizzle key (fr>>1)&3 ->
// 2-way banks (free, m136). V frags preloaded 2x16 to hide LDS latency
// under softmax / first MFMA half.
// ---------------------------------------------------------------------------
__global__ __launch_bounds__(256, 1) void attn_kernel(
    const u16* __restrict__ Qm, const u16* __restrict__ Km,
    const u16* __restrict__ Vt, u16* __restrict__ O) {
  __shared__ __align__(16) u16 Ks[2][32 * 512];   // 2 x 32KB
  __shared__ __align__(16) u16 Vs[2][512 * 32];   // 2 x 32KB

  const int tid = threadIdx.x;
  const int w = tid >> 6;
  const int lane = tid & 63;
  const int fr = lane & 15, fq = lane >> 4;
  const int s7 = fr & 7;
  const int nb = blockIdx.x & 7;   // batch -> XCD (round-robin dispatch)
  const int qt = blockIdx.x >> 3;

  // Q B-frags: lane fr = q-row (w*16+fr), fq*8 = d-chunk
  bf16x8 q[16];
  {
    const u16* Qb = Qm + ((int64_t)nb * QLEN + qt * 64 + w * 16 + fr) * EMBED + fq * 8;
#pragma unroll
    for (int kc = 0; kc < 16; ++kc) q[kc] = *(const bf16x8*)&Qb[kc * 32];
  }

  f32x4 o[32];  // o[dt][r]: q row w*16 + fq*4+r, d col dt*16+fr
#pragma unroll
  for (int i = 0; i < 32; ++i) o[i] = 0.0f;
  float mrun = -1e30f, lrun = 0.0f;  // per-lane scalars (q = fr)

  const u16* Kb = Km + (int64_t)nb * KLEN * EMBED;
  const u16* Vb = Vt + (int64_t)nb * (int64_t)EMBED * KLEN;

  // V staging source swizzle: lane l covers (d_local = l>>2, c_phys = l&3);
  // global chunk c_src = c_phys ^ ((d_local>>1)&3) = (l&3) ^ ((l>>3)&3).
  const int vrow = lane >> 2;
  const int vcl = (lane & 3) ^ ((lane >> 3) & 3);
  // V read swizzle (per dt): chunk = fq ^ ((fr>>1)&3)  -> 2-way banks, free
  const int vswz = ((fr >> 1) & 3);

  // prologue: stage K,V tile 0 into slot 0
  {
    const u16* srcK = Kb + (int64_t)(w * 8) * EMBED;
#pragma unroll
    for (int i = 0; i < 8; ++i)
      gload_lds16(srcK + (int64_t)i * EMBED + (lane ^ i) * 8, &Ks[0][(w * 8 + i) * 512]);
#pragma unroll
    for (int i = 0; i < 8; ++i) {
      const int row0 = w * 128 + i * 16;
      gload_lds16(Vb + (int64_t)(row0 + vrow) * KLEN + vcl * 8, &Vs[0][row0 * 32]);
    }
  }
  __syncthreads();

  const int NT = KLEN / 32;  // 128
  for (int t = 0; t < NT; ++t) {
    const int cur = t & 1;
    // prefetch K[t+1], V[t+1] into other slot (drained by iter-end sync)
    if (t + 1 < NT) {
      const u16* srcK = Kb + ((int64_t)(t + 1) * 32 + w * 8) * EMBED;
#pragma unroll
      for (int i = 0; i < 8; ++i)
        gload_lds16(srcK + (int64_t)i * EMBED + (lane ^ i) * 8,
                    &Ks[cur ^ 1][(w * 8 + i) * 512]);
#pragma unroll
      for (int i = 0; i < 8; ++i) {
        const int row0 = w * 128 + i * 16;
        gload_lds16(Vb + (int64_t)(row0 + vrow) * KLEN + (t + 1) * 32 + vcl * 8,
                    &Vs[cur ^ 1][row0 * 32]);
      }
    }

    // S^T = K Q^T: lane fr = q, keys ni*16 + fq*4 + r
    const u16* Kc = Ks[cur];
    f32x4 s0 = 0.0f, s1 = 0.0f;
#pragma unroll
    for (int kc = 0; kc < 16; ++kc) {
      bf16x8 k0 = *(const bf16x8*)&Kc[(fr)*512 + (((kc * 4 + fq) ^ s7) * 8)];
      bf16x8 k1 = *(const bf16x8*)&Kc[(16 + fr) * 512 + (((kc * 4 + fq) ^ s7) * 8)];
      s0 = __builtin_amdgcn_mfma_f32_16x16x32_bf16(k0, q[kc], s0, 0, 0, 0);
      s1 = __builtin_amdgcn_mfma_f32_16x16x32_bf16(k1, q[kc], s1, 0, 0, 0);
    }

    // first half of V fragments: issue now, latency hides under softmax VALU
    const u16* Vc = Vs[cur];
    bf16x8 vA[16];
#pragma unroll
    for (int dt = 0; dt < 16; ++dt)
      vA[dt] = *(const bf16x8*)&Vc[(dt * 16 + fr) * 32 + ((fq ^ vswz) * 8)];

    // in-register online softmax (defer-max, THR=8)
    float mt = fmaxf(fmaxf(fmaxf(s0[0], s0[1]), fmaxf(s0[2], s0[3])),
                     fmaxf(fmaxf(s1[0], s1[1]), fmaxf(s1[2], s1[3])));
    mt = fmaxf(mt, __shfl_xor(mt, 16));
    mt = fmaxf(mt, __shfl_xor(mt, 32));
    float alpha = 1.0f;
    if (!__all(mt <= mrun + 8.0f)) {
      const float mn = fmaxf(mrun, mt);
      alpha = __expf(mrun - mn);
      lrun *= alpha;
      mrun = mn;
    }
    float p0[4], p1[4];
    float rs = 0.0f;
#pragma unroll
    for (int r = 0; r < 4; ++r) {
      p0[r] = __expf(s0[r] - mrun);
      p1[r] = __expf(s1[r] - mrun);
      rs += p0[r] + p1[r];
    }
    rs += __shfl_xor(rs, 16);
    rs += __shfl_xor(rs, 32);
    lrun += rs;

    // pack p -> 4 dwords (lo = keys 0-15 slice, hi = keys 16-31 slice)
    const uint32_t lo0 = (uint32_t)f2bf(p0[0]) | ((uint32_t)f2bf(p0[1]) << 16);
    const uint32_t lo1 = (uint32_t)f2bf(p0[2]) | ((uint32_t)f2bf(p0[3]) << 16);
    const uint32_t hi0 = (uint32_t)f2bf(p1[0]) | ((uint32_t)f2bf(p1[1]) << 16);
    const uint32_t hi1 = (uint32_t)f2bf(p1[2]) | ((uint32_t)f2bf(p1[3]) << 16);
    // repack to PV A-frag: lane (fr,fq) needs k = fq*8..fq*8+7 for q=fr
    const int srcA = fr + (((fq << 1) & 3) << 4);
    const int srcB = srcA + 16;
    const bool useHi = (fq >= 2);
    const uint32_t aLo0 = __shfl(lo0, srcA), aHi0 = __shfl(hi0, srcA);
    const uint32_t aLo1 = __shfl(lo1, srcA), aHi1 = __shfl(hi1, srcA);
    const uint32_t bLo0 = __shfl(lo0, srcB), bHi0 = __shfl(hi0, srcB);
    const uint32_t bLo1 = __shfl(lo1, srcB), bHi1 = __shfl(hi1, srcB);
    u32x4 pd;
    pd[0] = useHi ? aHi0 : aLo0;
    pd[1] = useHi ? aHi1 : aLo1;
    pd[2] = useHi ? bHi0 : bLo0;
    pd[3] = useHi ? bHi1 : bLo1;
    const bf16x8 pb = __builtin_bit_cast(bf16x8, pd);

    // rescale o (o rows are q = fq*4+r -> fetch those rows' alphas)
    if (__any(alpha != 1.0f)) {
      float ra[4];
#pragma unroll
      for (int r = 0; r < 4; ++r) ra[r] = __shfl(alpha, (fq << 2) + r);
#pragma unroll
      for (int dt = 0; dt < 32; ++dt)
#pragma unroll
        for (int r = 0; r < 4; ++r) o[dt][r] *= ra[r];
    }

    // second half of V fragments: issue; latency hides under vA's MFMAs
    bf16x8 vB[16];
#pragma unroll
    for (int dt = 0; dt < 16; ++dt)
      vB[dt] = *(const bf16x8*)&Vc[((16 + dt) * 16 + fr) * 32 + ((fq ^ vswz) * 8)];

    // PV: o[dt] += pb (A: q-rows) x V B-frag
#pragma unroll
    for (int dt = 0; dt < 16; ++dt)
      o[dt] = __builtin_amdgcn_mfma_f32_16x16x32_bf16(pb, vA[dt], o[dt], 0, 0, 0);
#pragma unroll
    for (int dt = 0; dt < 16; ++dt)
      o[16 + dt] = __builtin_amdgcn_mfma_f32_16x16x32_bf16(pb, vB[dt], o[16 + dt],
                                                           0, 0, 0);

    __syncthreads();  // staging drain; all waves done reading cur slots
  }

  // normalize + store (l for q-row fq*4+r lives in lane fq*4+r)
  float linv[4];
#pragma unroll
  for (int r = 0; r < 4; ++r) linv[r] = 1.0f / __shfl(lrun, (fq << 2) + r);
  u16* Ob = O + ((int64_t)nb * QLEN + qt * 64 + w * 16) * EMBED;
#pragma unroll
  for (int dt = 0; dt < 32; ++dt)
#pragma unroll
    for (int r = 0; r < 4; ++r)
      Ob[(int64_t)((fq << 2) + r) * EMBED + dt * 16 + fr] = f2bf(o[dt][r] * linv[r]);
}

extern "C" void kernel_launch(void* const* d_in, const int* in_sizes, int n_in,
                              void* d_out, int out_size, void* d_ws, size_t ws_size,
                              hipStream_t stream) {
  const float* x  = (const float*)d_in[0];
  const float* y  = (const float*)d_in[1];
  const float* Wq = (const float*)d_in[2];
  const float* Wk = (const float*)d_in[3];
  const float* Wv = (const float*)d_in[4];
  const float* Wo = (const float*)d_in[5];
  const float* bo = (const float*)d_in[6];
  float* out = (float*)d_out;

  const int64_t nx = (int64_t)NBATCH * QLEN * EMBED;  // 8,388,608
  const int64_t ny = (int64_t)NBATCH * KLEN * EMBED;  // 16,777,216
  const int64_t nw = (int64_t)EMBED * EMBED;          // 262,144

  // ws layout (bf16): xb | yb | Wqb | Wkb | Wvb | Wob | Qm | Km | Vt  (~136MB)
  u16* w   = (u16*)d_ws;
  u16* xb  = w;            // dead after Q projection
  u16* O   = w; w += nx;   // attn output overlays xb
  u16* yb  = w; w += ny;
  u16* Wqb = w; w += nw;
  u16* Wkb = w; w += nw;
  u16* Wvb = w; w += nw;
  u16* Wob = w; w += nw;
  u16* Qm  = w; w += nx;
  u16* Km  = w; w += ny;
  u16* Vt  = w; w += ny;   // [8][512][4096]

  // one fused fp32->bf16 conversion over the contiguous region
  cvt_all_kernel<<<25600, 256, 0, stream>>>(x, y, Wq, Wk, Wv, Wo, xb);

  // Qm = (x@Wq^T) * 1/sqrt(512)
  const float scal = 0.04419417382415922f;
  gemm_bt<EPI_BF16_SCALE><<<dim3(128, 4, 1), 256, 0, stream>>>(
      xb, Wqb, Qm, 16384, EMBED, EMBED, scal, nullptr, nullptr);

  // fused K+V projection (shared A staging): Km row-major + Vt d-major
  gemm_kv<<<dim3(256, 4, 1), 256, 0, stream>>>(yb, Wkb, Wvb, Km, Vt);

  // fused attention (writes O over the dead xb slot)
  attn_kernel<<<NBATCH * 32, 256, 0, stream>>>(Qm, Km, Vt, O);

  // out = x + O @ Wo^T + bo   (fp32 epilogue)
  gemm_bt<EPI_F32_RESID><<<dim3(128, 4, 1), 256, 0, stream>>>(
      O, Wob, out, 16384, EMBED, EMBED, 1.f, x, bo);
}